// Round 16
// baseline (126.285 us; speedup 1.0000x reference)
//
#include <hip/hip_runtime.h>

#define NR   8192
#define CIN  200
#define CNN  128
#define BN_EPS 1e-5f

// ws float offsets
#define OFF_BNPART 0                           // 64 blocks * 400
#define OFF_DTH    (OFF_BNPART + 64 * 400)
#define OFF_V2     (OFF_DTH + NR * CNN)        // [NR][8] f32 (cols 0..4 used)
#define OFF_MPA    (OFF_V2 + NR * 8)           // 512 * 56 moment partials
#define OFF_MPB    (OFF_MPA + 512 * 56)
#define OFF_WT     (OFF_MPB + 512 * 56)        // wdtdT [128][128]
#define OFF_WBT    (OFF_WT + 128 * 128)        // [200][256]: w1^T | wdt^T

// moment tables: t<5 -> S1[A]; 5<=t<20 -> M2[A][B]; 20<=t<55 -> T3[A][B][C]
__device__ const int MA[55] = {0,1,2,3,4,
    0,0,0,0,0,1,1,1,1,2,2,2,3,3,4,
    0,0,0,0,0,0,0,0,0,0,0,0,0,0,0,
    1,1,1,1,1,1,1,1,1,1,
    2,2,2,2,2,2,
    3,3,3,
    4};
__device__ const int MB[55] = {-1,-1,-1,-1,-1,
    0,1,2,3,4,1,2,3,4,2,3,4,3,4,4,
    0,0,0,0,0,1,1,1,1,2,2,2,3,3,4,
    1,1,1,1,2,2,2,3,3,4,
    2,2,2,3,3,4,
    3,3,4,
    4};
__device__ const int MC[55] = {-1,-1,-1,-1,-1,
    -1,-1,-1,-1,-1,-1,-1,-1,-1,-1,-1,-1,-1,-1,-1,
    0,1,2,3,4,1,2,3,4,2,3,4,3,4,4,
    1,2,3,4,2,3,4,3,4,4,
    2,3,4,3,4,4,
    3,4,4,
    4};

// ---- BN partials (0..63) + w1/wdt transpose (64..83) + wdtd^T (84..99) ----
__global__ __launch_bounds__(256) void bn1_k(
    const float* __restrict__ H, const float* __restrict__ w1,
    const float* __restrict__ wdt, const float* __restrict__ wdtd,
    float* __restrict__ ws)
{
    const int t = threadIdx.x, b = blockIdx.x;
    if (b < 64) {
        if (t >= CIN) return;
        const float* p = H + (size_t)b * 128 * CIN + t;
        float s = 0.f, q = 0.f;
        #pragma unroll 8
        for (int r = 0; r < 128; ++r) { float v = p[(size_t)r * CIN]; s += v; q += v * v; }
        ws[OFF_BNPART + b * 400 + t]       = s;
        ws[OFF_BNPART + b * 400 + 200 + t] = q;
    } else if (b < 84) {
        float* wT = ws + OFF_WBT;
        #pragma unroll
        for (int i = 0; i < 10; ++i) {
            const int idx = (b - 64) * 2560 + t + i * 256;   // 0..51199
            const int k = idx >> 8, n = idx & 255;
            wT[idx] = (n < 128) ? w1[(size_t)n * CIN + k]
                                : wdt[(size_t)(n - 128) * CIN + k];
        }
    } else {
        const int n0 = (b - 84) * 8;
        float* wT = ws + OFF_WT;
        #pragma unroll
        for (int i = 0; i < 4; ++i) {
            const int idx = t + i * 256;
            const int dn = idx >> 7, k = idx & 127;
            wT[k * 128 + n0 + dn] = wdtd[(size_t)(n0 + dn) * 128 + k];
        }
    }
}

// ---- BN finalize + barrier-free dual GEMM + l12 + moments (512x512) -------
__global__ __launch_bounds__(512) void gemm_bn_k(
    const float* __restrict__ H, const float* __restrict__ b1,
    const float* __restrict__ bdt,
    const float* __restrict__ aw1, const float* __restrict__ ab1,
    const float* __restrict__ aw2, const float* __restrict__ ab2,
    const float* __restrict__ gamma, const float* __restrict__ beta,
    float* __restrict__ ws, float* __restrict__ DTH,
    float* __restrict__ V2g, float* __restrict__ mpart)
{
    __shared__ float A_lds[16 * 200];       // A tile; reused as Ct[16*136]
    __shared__ float scs[200], shs[200], bias[256];
    __shared__ float aw1t[1280];            // [k*10+o]
    __shared__ float aw2s[52], ab1s[12], ab2s[8];
    __shared__ float v1s[16 * 12], v2row[16 * 6];

    const int t   = threadIdx.x;
    const int m0  = blockIdx.x * 16;
    const float* bnpart = ws + OFF_BNPART;

    for (int i = t; i < 1280; i += 512) {
        const int o = i >> 7, k = i & 127;
        aw1t[k * 10 + o] = aw1[i];
    }
    if (t < CIN) {
        float s = 0.f, q = 0.f;
        const float* p = bnpart + t;
        #pragma unroll 8
        for (int b = 0; b < 64; ++b) { s += p[b * 400]; q += p[b * 400 + 200]; }
        float mu  = s * (1.f / NR);
        float var = q * (1.f / NR) - mu * mu;
        float sc  = rsqrtf(var + BN_EPS) * gamma[t];
        scs[t] = sc; shs[t] = beta[t] - mu * sc;
    }
    if (t < 256) bias[t] = (t < 128) ? b1[t] : bdt[t - 128];
    if (t < 50) aw2s[t] = aw2[t];
    if (t < 10) ab1s[t] = ab1[t];
    if (t < 5)  ab2s[t] = ab2[t];
    __syncthreads();

    // build A[16][200] = BN(H rows)
    #pragma unroll
    for (int i = 0; i < 7; ++i) {
        const int idx = t + i * 512;
        if (idx < 3200) {
            const int m = idx / 200, k = idx - m * 200;
            A_lds[idx] = H[(size_t)(m0 + m) * CIN + k] * scs[k] + shs[k];
        }
    }
    __syncthreads();

    // barrier-free GEMM: thread owns col n (0..255), 8 rows
    const float* wTg = ws + OFF_WBT;
    const int n = t & 255, rg = t >> 8;
    float acc[8] = {};
    for (int k4 = 0; k4 < 50; ++k4) {
        const int k = k4 * 4;
        const float w0  = wTg[(k + 0) * 256 + n];
        const float w1v = wTg[(k + 1) * 256 + n];
        const float w2v = wTg[(k + 2) * 256 + n];
        const float w3v = wTg[(k + 3) * 256 + n];
        #pragma unroll
        for (int i = 0; i < 8; ++i) {
            const int m = rg * 8 + i;
            float4 av = *(const float4*)&A_lds[m * 200 + k];
            acc[i] += av.x * w0 + av.y * w1v + av.z * w2v + av.w * w3v;
        }
    }
    __syncthreads();                         // done reading A_lds

    if (n < 128) {                           // V tile -> Ct (LDS only)
        #pragma unroll
        for (int i = 0; i < 8; ++i) {
            const int m = rg * 8 + i;
            A_lds[m * 136 + n] = fmaxf(acc[i] + bias[n], 0.f);
        }
    } else {                                 // DTH -> global
        #pragma unroll
        for (int i = 0; i < 8; ++i) {
            const int m = rg * 8 + i;
            DTH[(size_t)(m0 + m) * CNN + (n - 128)] = acc[i] + bias[n];
        }
    }
    __syncthreads();

    if (t < 160) {
        const int r = t / 10, o = t % 10;
        float s = ab1s[o];
        #pragma unroll 8
        for (int k = 0; k < 128; ++k) s += A_lds[r * 136 + k] * aw1t[k * 10 + o];
        v1s[r * 12 + o] = fmaxf(s, 0.f);
    }
    __syncthreads();
    if (t < 16) {
        float vv[10];
        #pragma unroll
        for (int o = 0; o < 10; ++o) vv[o] = v1s[t * 12 + o];
        #pragma unroll
        for (int p = 0; p < 5; ++p) {
            float s = ab2s[p];
            #pragma unroll
            for (int o = 0; o < 10; ++o) s += aw2s[p * 10 + o] * vv[o];
            float val = fmaxf(s, 0.f);
            v2row[t * 6 + p] = val;
            V2g[(size_t)(m0 + t) * 8 + p] = val;
        }
    }
    __syncthreads();
    if (t < 55) {
        const int a = MA[t], b = MB[t], c = MC[t];
        float s = 0.f;
        #pragma unroll
        for (int r = 0; r < 16; ++r) {
            float p = v2row[r * 6 + a];
            if (b >= 0) p *= v2row[r * 6 + b];
            if (c >= 0) p *= v2row[r * 6 + c];
            s += p;
        }
        mpart[blockIdx.x * 56 + t] = s;
    }
}

// ---- iteration: moment attention + L4 head + barrier-free GEMM ------------
// 512 blocks x 16 rows, 256 threads. Last iteration fuses outV + H_R.
__global__ __launch_bounds__(256) void iter_k(
    const float* __restrict__ DTH, const float* __restrict__ V2g_in,
    const float* __restrict__ mpartIn,
    const float* __restrict__ alpha_p,
    const float* __restrict__ wdtdT, const float* __restrict__ bdtd,
    const float* __restrict__ aw4, const float* __restrict__ ab4,
    const float* __restrict__ aw1, const float* __restrict__ ab1,
    const float* __restrict__ aw2, const float* __restrict__ ab2,
    const float* __restrict__ aw3, const float* __restrict__ ab3,
    const float* __restrict__ wdt,
    float* __restrict__ V2g_out, float* __restrict__ mpartOut,
    float* __restrict__ outV, float* __restrict__ outHR)
{
    __shared__ float A_lds[16 * 136];   // A tile; reused as Ct post-GEMM
    __shared__ float w4s[1280], aw1t[1280];
    __shared__ float b4s[128], bds[128];
    __shared__ float aw2s[52], ab1s[12], ab2s[8], w3s[52], b3s[12];
    __shared__ float v4s[16 * 12], v1s[16 * 12], v2row[16 * 6];
    __shared__ float S1s[8], M2f[25], T3f[125];
    __shared__ float redm[224];

    const int t  = threadIdx.x;
    const int m0 = blockIdx.x * 16;
    const bool last = (outV != nullptr);

    for (int i = t; i < 1280; i += 256) {
        w4s[i] = aw4[i];
        const int o = i >> 7, k = i & 127;
        aw1t[k * 10 + o] = aw1[i];
    }
    if (t < 128) { b4s[t] = ab4[t]; bds[t] = bdtd[t]; }
    if (t < 50)  { aw2s[t] = aw2[t]; w3s[t] = aw3[t]; }
    if (t < 10)  { ab1s[t] = ab1[t]; b3s[t] = ab3[t]; }
    if (t < 5)   ab2s[t] = ab2[t];

    // reduce 512 moment partials -> 55 moments
    if (t < 224) {
        const int c = t % 56, g0 = t / 56;
        float s = 0.f;
        for (int g = g0; g < 8; g += 4) {
            const float* p = mpartIn + (size_t)g * 64 * 56 + c;
            #pragma unroll 8
            for (int j = 0; j < 64; ++j) s += p[j * 56];
        }
        redm[t] = s;
    }
    __syncthreads();
    if (t < 55) {
        float v = redm[t] + redm[56 + t] + redm[112 + t] + redm[168 + t];
        const int a = MA[t], b = MB[t], c = MC[t];
        if (t < 5)       S1s[t] = v;
        else if (t < 20) { M2f[a * 5 + b] = v; M2f[b * 5 + a] = v; }
        else {
            T3f[(a * 5 + b) * 5 + c] = v; T3f[(a * 5 + c) * 5 + b] = v;
            T3f[(b * 5 + a) * 5 + c] = v; T3f[(b * 5 + c) * 5 + a] = v;
            T3f[(c * 5 + a) * 5 + b] = v; T3f[(c * 5 + b) * 5 + a] = v;
        }
    }
    __syncthreads();

    // per-row Taylor-softmax + L3 -> v4s
    if (t < 16) {
        float q[5];
        #pragma unroll
        for (int c = 0; c < 5; ++c) q[c] = V2g_in[(size_t)(m0 + t) * 8 + c];
        float denom = (float)NR;
        float num[5];
        #pragma unroll
        for (int c = 0; c < 5; ++c) num[c] = S1s[c];
        #pragma unroll
        for (int a = 0; a < 5; ++a) {
            denom += q[a] * S1s[a];
            #pragma unroll
            for (int c = 0; c < 5; ++c) num[c] += q[a] * M2f[a * 5 + c];
        }
        #pragma unroll
        for (int a = 0; a < 5; ++a) {
            #pragma unroll
            for (int b = 0; b < 5; ++b) {
                const float w = 0.5f * q[a] * q[b];
                denom += w * M2f[a * 5 + b];
                #pragma unroll
                for (int c = 0; c < 5; ++c) num[c] += w * T3f[(a * 5 + b) * 5 + c];
            }
        }
        const float inv = 1.f / denom;
        float av[5];
        #pragma unroll
        for (int c = 0; c < 5; ++c) av[c] = num[c] * inv;
        #pragma unroll
        for (int o = 0; o < 10; ++o) {
            float s = b3s[o];
            #pragma unroll
            for (int c = 0; c < 5; ++c) s += w3s[o * 5 + c] * av[c];
            v4s[t * 12 + o] = fmaxf(s, 0.f);
        }
    }
    __syncthreads();

    // build A[16][128] in LDS: DTH + alpha*relu(L4 head)
    const float alpha = alpha_p[0];
    #pragma unroll
    for (int i = 0; i < 8; ++i) {
        const int idx = t + i * 256;
        const int m = idx >> 7, k = idx & 127;
        float pre = b4s[k];
        #pragma unroll
        for (int o = 0; o < 10; ++o) pre += w4s[k * 10 + o] * v4s[m * 12 + o];
        A_lds[m * 136 + k] = DTH[(size_t)(m0 + m) * CNN + k] + alpha * fmaxf(pre, 0.f);
    }
    __syncthreads();

    // barrier-free GEMM: thread owns col n, 8 rows
    const int n = t & 127, rg = t >> 7;
    float acc[8] = {};
    #pragma unroll 4
    for (int k4 = 0; k4 < 32; ++k4) {
        const int k = k4 * 4;
        const float w0 = wdtdT[(size_t)(k + 0) * 128 + n];
        const float w1v = wdtdT[(size_t)(k + 1) * 128 + n];
        const float w2v = wdtdT[(size_t)(k + 2) * 128 + n];
        const float w3v = wdtdT[(size_t)(k + 3) * 128 + n];
        #pragma unroll
        for (int i = 0; i < 8; ++i) {
            const int m = rg * 8 + i;
            float4 av = *(const float4*)&A_lds[m * 136 + k];
            acc[i] += av.x * w0 + av.y * w1v + av.z * w2v + av.w * w3v;
        }
    }
    __syncthreads();                       // done reading A_lds

    if (!last) {
        #pragma unroll
        for (int i = 0; i < 8; ++i) {
            const int m = rg * 8 + i;
            A_lds[m * 136 + n] = fmaxf(acc[i] + bds[n], 0.f);   // Ct
        }
        __syncthreads();
        if (t < 160) {
            const int r = t / 10, o = t % 10;
            float s = ab1s[o];
            #pragma unroll 8
            for (int k = 0; k < 128; ++k) s += A_lds[r * 136 + k] * aw1t[k * 10 + o];
            v1s[r * 12 + o] = fmaxf(s, 0.f);
        }
        __syncthreads();
        if (t < 16) {
            float vv[10];
            #pragma unroll
            for (int o = 0; o < 10; ++o) vv[o] = v1s[t * 12 + o];
            #pragma unroll
            for (int p = 0; p < 5; ++p) {
                float s = ab2s[p];
                #pragma unroll
                for (int o = 0; o < 10; ++o) s += aw2s[p * 10 + o] * vv[o];
                float val = fmaxf(s, 0.f);
                v2row[t * 6 + p] = val;
                V2g_out[(size_t)(m0 + t) * 8 + p] = val;
            }
        }
        __syncthreads();
        if (t < 55) {
            const int a = MA[t], b = MB[t], c = MC[t];
            float s = 0.f;
            #pragma unroll
            for (int r = 0; r < 16; ++r) {
                float p = v2row[r * 6 + a];
                if (b >= 0) p *= v2row[r * 6 + b];
                if (c >= 0) p *= v2row[r * 6 + c];
                s += p;
            }
            mpartOut[blockIdx.x * 56 + t] = s;
        }
    } else {
        // final: write V (global + Ct in LDS), then fused H_R = Ct @ wdt
        #pragma unroll
        for (int i = 0; i < 8; ++i) {
            const int m = rg * 8 + i;
            const float v = fmaxf(acc[i] + bds[n], 0.f);
            A_lds[m * 136 + n] = v;
            outV[(size_t)(m0 + m) * CNN + n] = v;
        }
        __syncthreads();
        if (t < CIN) {
            float hr[16];
            #pragma unroll
            for (int i = 0; i < 16; ++i) hr[i] = 0.f;
            for (int k = 0; k < 128; ++k) {
                const float wk = wdt[(size_t)k * CIN + t];
                #pragma unroll
                for (int i = 0; i < 16; ++i) hr[i] += A_lds[i * 136 + k] * wk;
            }
            #pragma unroll
            for (int i = 0; i < 16; ++i)
                outHR[(size_t)(m0 + i) * CIN + t] = hr[i];
        }
    }
}

// --------------------------------------------------------------- launcher
extern "C" void kernel_launch(void* const* d_in, const int* in_sizes, int n_in,
                              void* d_out, int out_size, void* d_ws, size_t ws_size,
                              hipStream_t stream)
{
    (void)in_sizes; (void)n_in; (void)out_size; (void)ws_size;
    const float* H     = (const float*)d_in[0];
    const float* alpha = (const float*)d_in[1];
    const float* gamma = (const float*)d_in[2];
    const float* beta  = (const float*)d_in[3];
    const float* w1    = (const float*)d_in[4];
    const float* b1    = (const float*)d_in[5];
    const float* wdt   = (const float*)d_in[6];
    const float* bdt   = (const float*)d_in[7];
    const float* wdtd  = (const float*)d_in[8];
    const float* bdtd  = (const float*)d_in[9];
    const float* aw1   = (const float*)d_in[10];
    const float* ab1   = (const float*)d_in[11];
    const float* aw2   = (const float*)d_in[12];
    const float* ab2   = (const float*)d_in[13];
    const float* aw3   = (const float*)d_in[14];
    const float* ab3   = (const float*)d_in[15];
    const float* aw4   = (const float*)d_in[16];
    const float* ab4   = (const float*)d_in[17];

    float* ws    = (float*)d_ws;
    float* DTH   = ws + OFF_DTH;
    float* V2g   = ws + OFF_V2;
    float* mpA   = ws + OFF_MPA;
    float* mpB   = ws + OFF_MPB;
    float* wdtdT = ws + OFF_WT;

    float* outV  = (float*)d_out;
    float* outHR = outV + (size_t)NR * CNN;

    bn1_k<<<100, 256, 0, stream>>>(H, w1, wdt, wdtd, ws);
    gemm_bn_k<<<512, 512, 0, stream>>>(H, b1, bdt, aw1, ab1, aw2, ab2,
                                       gamma, beta, ws, DTH, V2g, mpA);
    iter_k<<<512, 256, 0, stream>>>(DTH, V2g, mpA, alpha, wdtdT, bdtd,
                                    aw4, ab4, aw1, ab1, aw2, ab2, aw3, ab3, wdt,
                                    V2g, mpB, nullptr, nullptr);
    iter_k<<<512, 256, 0, stream>>>(DTH, V2g, mpB, alpha, wdtdT, bdtd,
                                    aw4, ab4, aw1, ab1, aw2, ab2, aw3, ab3, wdt,
                                    V2g, mpA, nullptr, nullptr);
    iter_k<<<512, 256, 0, stream>>>(DTH, V2g, mpA, alpha, wdtdT, bdtd,
                                    aw4, ab4, aw1, ab1, aw2, ab2, aw3, ab3, wdt,
                                    nullptr, nullptr, outV, outHR);
}